// Round 9
// baseline (248.708 us; speedup 1.0000x reference)
//
#include <hip/hip_runtime.h>
#include <math.h>

// FilterDetection: score threshold + morphological opening (erode 4x4,
// dilate 4x4) on 32x1024x1024 f32.
//
// Round-9: BRANCH-FREE unrolled body. Rounds 2-8 all had a runtime
// wave-uniform branch `if (t>=0 && t<H)` around the loads; under full unroll
// it split the body into 22 basic blocks and the compiler never hoisted
// global loads across them -> full load latency exposed every iteration
// (VALUBusy 17%, VGPR 64, dur pinned ~91-104us). Fix: clamp the row index so
// loads are unconditional, fold row validity via 11 v_cndmask selects on the
// hmin results. Only compile-time conditionals remain -> one straight-line
// block -> scheduler hoists loads iterations ahead (VGPR budget 128).
//
// Layout: 8 cols/lane, one wave = one 512-col segment of a 16-row strip.
// Per row: 4 dword-aligned vector loads (cols c0-3..c0+10), hmin(11),
// sliding 4-row vmin, OOB fold to -inf, hmax(8), sliding 4-row vmax,
// 2x float4 store. No LDS/barriers/cross-lane. 1024 mask blocks = 4/CU.
//
// Threshold deferred to store (monotone th() commutes with min/max; absmax=0
// rounds 1-8). Store guard it>=6 keeps writes strictly inside the strip
// (round-6 race). Plain coherent stores only (round-5 nt hazard).
//
// Window geometry: erode offsets [-2..+1] (OOB +inf); dilate [-1..+2]
// (OOB -inf). Output col j needs raw cols j-3..j+3.

#define H 1024
#define W 1024
#define R 16
#define STRIPS (H / R)                    // 64
#define SEGS 2                            // 512-col segments per row
#define BATCH 32
#define TASKS (STRIPS * SEGS * BATCH)     // 4096 wave-tasks
#define MASK_BLOCKS (TASKS / 4)           // 1024 blocks, 4 waves each
#define N_SCORE 32000
#define SCORE_BLOCKS ((N_SCORE + 255) / 256)

__device__ __forceinline__ float th(float v) { return v >= 0.5f ? v : 0.0f; }

__global__ __launch_bounds__(256, 4)
void fused_kernel(const float* __restrict__ score,
                  const float* __restrict__ mask,
                  float* __restrict__ out) {
    const int bid = blockIdx.x;
    const int tid = threadIdx.x;

    if (bid >= MASK_BLOCKS) {               // tail blocks: score threshold
        int i = (bid - MASK_BLOCKS) * 256 + tid;
        if (i < N_SCORE) out[i] = th(score[i]);
        return;
    }

    const int wave = tid >> 6;
    const int lane = tid & 63;
    const int task = bid * 4 + wave;        // one wave = one (img,strip,seg)
    const int b    = task >> 7;             // 128 tasks per image
    const int rem  = task & 127;
    const int strip= rem >> 1;
    const int seg  = rem & 1;
    const int y0   = strip * R;
    const int c0   = seg * 512 + lane * 8;  // first of this lane's 8 columns

    const float* img  = mask + (size_t)b * (H * W);
    float*       outp = out + N_SCORE + (size_t)b * (H * W);

    const bool eL = (c0 == 0);              // needs cols < 0 (pad)
    const bool eR = (c0 == W - 8);          // needs cols >= W (pad)
    // Clamped load offsets (floats), all guaranteed in [0, W-4]/[0, W-2]:
    const int o0 = eL ? 0       : (c0 - 3); // raw cols c0-3..c0   (4)
    const int o1 = c0 + 1;                  // raw cols c0+1..c0+4 (4)
    const int o2 = eR ? (W - 4) : (c0 + 5); // raw cols c0+5..c0+8 (4)
    const int o3 = eR ? (W - 2) : (c0 + 9); // raw cols c0+9..c0+10 (2)

    // Eroded-col mask for ec index m (col c0-1+m): +inf keeps, -inf pads.
    float cm[11];
    #pragma unroll
    for (int m = 0; m < 11; ++m) {
        int col = c0 - 1 + m;
        cm[m] = (col >= 0 && col < W) ? INFINITY : -INFINITY;
    }

    // Sliding windows: 3 history rows + current.
    float hmw0[11], hmw1[11], hmw2[11];     // hmin rows t-1, t-2, t-3
    float hxw0[8],  hxw1[8],  hxw2[8];      // hmax rows r-1, r-2, r-3
    #pragma unroll
    for (int m = 0; m < 11; ++m) { hmw0[m] = hmw1[m] = hmw2[m] = INFINITY; }
    #pragma unroll
    for (int j = 0; j < 8; ++j)  { hxw0[j] = hxw1[j] = hxw2[j] = -INFINITY; }

    #pragma unroll
    for (int it = 0; it < R + 6; ++it) {
        const int t  = y0 - 3 + it;         // raw row consumed this iteration
        // Branch-free: always load from a clamped valid row, select later.
        const int tc = (t < 0) ? 0 : ((t >= H) ? (H - 1) : t);
        const bool rowok = (t >= 0) && (t < H);

        const float* row = img + (size_t)tc * W;
        float4 L0, L1, L2; float2 L3;
        __builtin_memcpy(&L0, row + o0, 16);   // dword-aligned dwordx4
        __builtin_memcpy(&L1, row + o1, 16);
        __builtin_memcpy(&L2, row + o2, 16);
        __builtin_memcpy(&L3, row + o3, 8);

        float ar[14];
        ar[0]  = eL ? INFINITY : L0.x;   // col c0-3
        ar[1]  = eL ? INFINITY : L0.y;   // col c0-2
        ar[2]  = eL ? INFINITY : L0.z;   // col c0-1
        ar[3]  = eL ? L0.x     : L0.w;   // col c0
        ar[4]  = L1.x;  ar[5] = L1.y;  ar[6] = L1.z;  ar[7] = L1.w;
        ar[8]  = eR ? L2.y : L2.x;       // col c0+5
        ar[9]  = eR ? L2.z : L2.y;       // col c0+6
        ar[10] = eR ? L2.w : L2.z;       // col c0+7
        ar[11] = eR ? INFINITY : L2.w;   // col c0+8
        ar[12] = eR ? INFINITY : L3.x;   // col c0+9
        ar[13] = eR ? INFINITY : L3.y;   // col c0+10

        // ---- hmin row t for cols c0-1+m (m=0..10): raw window ar[m..m+3];
        //      invalid rows contribute +inf (erosion identity) ----
        float hm[11];
        #pragma unroll
        for (int m = 0; m < 11; ++m) {
            float v = fminf(fminf(ar[m], ar[m + 1]), fminf(ar[m + 2], ar[m + 3]));
            hm[m] = rowok ? v : INFINITY;
        }

        // ---- eroded row r = t-1: vertical min rows t-3..t, OOB -> -inf ----
        const int r = t - 1;
        const float rlim = (r >= 0 && r < H) ? INFINITY : -INFINITY;  // uniform
        float ec[11];
        #pragma unroll
        for (int m = 0; m < 11; ++m) {
            float e = fminf(fminf(hmw2[m], hmw1[m]), fminf(hmw0[m], hm[m]));
            ec[m] = fminf(fminf(e, cm[m]), rlim);
        }

        // shift hmin history (renamed under full unroll)
        #pragma unroll
        for (int m = 0; m < 11; ++m) { hmw2[m] = hmw1[m]; hmw1[m] = hmw0[m]; hmw0[m] = hm[m]; }

        // ---- hmax row r, col c0+j: eroded window ec[j..j+3] ----
        float hx[8];
        #pragma unroll
        for (int j = 0; j < 8; ++j)
            hx[j] = fmaxf(fmaxf(ec[j], ec[j + 1]), fmaxf(ec[j + 2], ec[j + 3]));

        // ---- output row y = t-3 = y0-6+it: vertical max hx rows y-1..y+2.
        //      it>=6 is compile-time under full unroll (no runtime branch) ----
        if (it >= 6) {
            const int y = t - 3;
            float o[8];
            #pragma unroll
            for (int j = 0; j < 8; ++j)
                o[j] = th(fmaxf(fmaxf(hxw2[j], hxw1[j]), fmaxf(hxw0[j], hx[j])));
            float* po = outp + (size_t)y * W + c0;
            float4 s0 = make_float4(o[0], o[1], o[2], o[3]);
            float4 s1 = make_float4(o[4], o[5], o[6], o[7]);
            *(float4*)(po)     = s0;
            *(float4*)(po + 4) = s1;
        }

        // shift hmax history
        #pragma unroll
        for (int j = 0; j < 8; ++j) { hxw2[j] = hxw1[j]; hxw1[j] = hxw0[j]; hxw0[j] = hx[j]; }
    }
}

extern "C" void kernel_launch(void* const* d_in, const int* in_sizes, int n_in,
                              void* d_out, int out_size, void* d_ws, size_t ws_size,
                              hipStream_t stream) {
    const float* score = (const float*)d_in[0];
    const float* mask  = (const float*)d_in[1];
    float* out = (float*)d_out;

    const int grid = MASK_BLOCKS + SCORE_BLOCKS;
    fused_kernel<<<grid, 256, 0, stream>>>(score, mask, out);
}